// Round 3
// baseline (692.736 us; speedup 1.0000x reference)
//
#include <hip/hip_runtime.h>

typedef unsigned short u16;
typedef __attribute__((ext_vector_type(8))) short bf16x8;
typedef __attribute__((ext_vector_type(4))) float f32x4;

#define BB 64
#define NN 5000
#define DD 128
#define EROW 640128   // (NN+1)*DD
#define CROW 640000   // NN*DD

__device__ __forceinline__ u16 f2bf(float f){
  unsigned u = __builtin_bit_cast(unsigned, f);
  u += 0x7fffu + ((u >> 16) & 1u);   // round-to-nearest-even
  return (u16)(u >> 16);
}
__device__ __forceinline__ float bf2f(u16 h){
  unsigned u = ((unsigned)h) << 16;
  return __builtin_bit_cast(float, u);
}
__device__ __forceinline__ bf16x8 pack8(float4 a, float4 b){
  bf16x8 r;
  r[0] = (short)f2bf(a.x); r[1] = (short)f2bf(a.y);
  r[2] = (short)f2bf(a.z); r[3] = (short)f2bf(a.w);
  r[4] = (short)f2bf(b.x); r[5] = (short)f2bf(b.y);
  r[6] = (short)f2bf(b.z); r[7] = (short)f2bf(b.w);
  return r;
}

#define LGKM0() do{ asm volatile("s_waitcnt lgkmcnt(0)" ::: "memory"); \
                    __builtin_amdgcn_sched_barrier(0); }while(0)

// ---------------- k0: weight bf16 conversion, accumulator zeroing, depot copy ----------------
__global__ __launch_bounds__(256) void k0_prep(
    const float* __restrict__ wl, const float* __restrict__ wr,
    const float* __restrict__ wcmb, const float* __restrict__ wff,
    const float* __restrict__ emb, float* __restrict__ out,
    u16* __restrict__ wbf, float* __restrict__ sums, float* __restrict__ sumsq)
{
  int t = blockIdx.x * 256 + threadIdx.x;   // grid covers exactly 81920
  if      (t < 16384) wbf[t] = f2bf(wl[t]);
  else if (t < 32768) wbf[t] = f2bf(wr[t - 16384]);
  else if (t < 65536) wbf[t] = f2bf(wcmb[t - 32768]);
  else                wbf[t] = f2bf(wff[t - 65536]);
  if (t < 8192){
    sums[t] = 0.f; sumsq[t] = 0.f;
    int b = t >> 7, d = t & 127;
    out[(size_t)b * EROW + d] = emb[(size_t)b * EROW + d];   // depot row passthrough
  }
}

// ---------------- k1: barrier-free per-wave fused pipeline ----------------
// Each wave independently computes 32 rows x 128 cols through all 3 GEMMs,
// with swapped MFMA operands: D^T = mfma(W_frag, act_frag).
//   W-frag  (1st op): lane(q,c) holds W[t*16+c][kt*32+q*8 .. +7]
//   act-frag(2nd op): lane(q,c) holds act[m-tile*16+c][kt*32+q*8 .. +7]
//   D:                lane(q,c) holds D^T[n=t*16+q*4+r][m=mtile*16+c]
// Inter-GEMM transpose via wave-PRIVATE LDS scratch (lgkmcnt-only, NO s_barrier).
template<bool BF>
__global__ __launch_bounds__(256, 2)
void k1_main(const int2* __restrict__ sol, const float* __restrict__ emb,
             const u16* __restrict__ wbf, const float* __restrict__ b_comb,
             const float* __restrict__ b_ff, float* __restrict__ out,
             u16* __restrict__ abuf, float* __restrict__ sums, float* __restrict__ sumsq)
{
  const int tid  = threadIdx.x;
  const int lane = tid & 63;
  const int w    = tid >> 6;       // wave 0..3
  const int q    = lane >> 4;
  const int c    = lane & 15;
  const int b    = blockIdx.y;
  const int R0   = blockIdx.x * 128 + w * 32;   // first customer row (0-based) of this wave

  // per-wave private scratch: [32 rows][136 cols] bf16 (272B stride, 16B aligned)
  __shared__ u16 scr_all[4][32][136];
  u16 (*scr)[136] = scr_all[w];

  const float* embB = emb + (size_t)b * EROW;
  const u16* wl = wbf;            // [128][128]
  const u16* wr = wbf + 16384;    // [128][128]
  const u16* wc = wbf + 32768;    // [128][256]
  const u16* wf = wbf + 65536;    // [128][128]

  // biases, lane view: n = t*16 + q*4 + r
  f32x4 bcv[8], bfv[8];
  #pragma unroll
  for (int t = 0; t < 8; ++t){
    bcv[t] = *(const f32x4*)(b_comb + t*16 + q*4);
    bfv[t] = *(const f32x4*)(b_ff  + t*16 + q*4);
  }

  // ---- gather left/right fragments straight from global (no LDS stage) ----
  int iL[2], iR[2];
  #pragma unroll
  for (int mm = 0; mm < 2; ++mm){
    int r = min(R0 + mm*16 + c, NN - 1);
    int2 p = sol[(size_t)b * NN + r];
    iL[mm] = p.x; iR[mm] = p.y;
  }
  bf16x8 lF[2][4], rF[2][4];
  #pragma unroll
  for (int mm = 0; mm < 2; ++mm){
    const float* pL = embB + (size_t)iL[mm] * DD + q*8;
    const float* pR = embB + (size_t)iR[mm] * DD + q*8;
    #pragma unroll
    for (int kt = 0; kt < 4; ++kt){
      float4 a0 = *(const float4*)(pL + kt*32);
      float4 a1 = *(const float4*)(pL + kt*32 + 4);
      float4 b0 = *(const float4*)(pR + kt*32);
      float4 b1 = *(const float4*)(pR + kt*32 + 4);
      lF[mm][kt] = pack8(a0, a1);
      rF[mm][kt] = pack8(b0, b1);
    }
  }

  const f32x4 fz = {0.f, 0.f, 0.f, 0.f};
  f32x4 acc[8][2];

  // ---- GEMM1: info^T = Wl . left^T + Wr . right^T ----
  #pragma unroll
  for (int t = 0; t < 8; ++t){ acc[t][0] = fz; acc[t][1] = fz; }
  #pragma unroll
  for (int t = 0; t < 8; ++t){
    const int wrow = (t*16 + c) * DD + q*8;
    #pragma unroll
    for (int kt = 0; kt < 4; ++kt){
      bf16x8 wlf = *(const bf16x8*)(wl + wrow + kt*32);
      #pragma unroll
      for (int mm = 0; mm < 2; ++mm)
        acc[t][mm] = __builtin_amdgcn_mfma_f32_16x16x32_bf16(wlf, lF[mm][kt], acc[t][mm], 0, 0, 0);
    }
    #pragma unroll
    for (int kt = 0; kt < 4; ++kt){
      bf16x8 wrf = *(const bf16x8*)(wr + wrow + kt*32);
      #pragma unroll
      for (int mm = 0; mm < 2; ++mm)
        acc[t][mm] = __builtin_amdgcn_mfma_f32_16x16x32_bf16(wrf, rF[mm][kt], acc[t][mm], 0, 0, 0);
    }
  }

  // info -> scratch [m][n] (bf16), transposing D layout via LDS
  #pragma unroll
  for (int t = 0; t < 8; ++t){
    #pragma unroll
    for (int mm = 0; mm < 2; ++mm){
      ushort4 u;
      u.x = f2bf(acc[t][mm][0]); u.y = f2bf(acc[t][mm][1]);
      u.z = f2bf(acc[t][mm][2]); u.w = f2bf(acc[t][mm][3]);
      *(ushort4*)&scr[mm*16 + c][t*16 + q*4] = u;
    }
  }

  // cust fragments (contiguous rows R0+1.., latency overlaps the LDS writes above)
  bf16x8 cF[2][4];
  #pragma unroll
  for (int mm = 0; mm < 2; ++mm){
    int crow = min(R0 + mm*16 + c + 1, NN);
    const float* pC = embB + (size_t)crow * DD + q*8;
    #pragma unroll
    for (int kt = 0; kt < 4; ++kt){
      float4 a0 = *(const float4*)(pC + kt*32);
      float4 a1 = *(const float4*)(pC + kt*32 + 4);
      cF[mm][kt] = pack8(a0, a1);
    }
  }

  LGKM0();   // wave-private: info writes visible to this wave's reads

  bf16x8 iF[2][4];
  #pragma unroll
  for (int mm = 0; mm < 2; ++mm)
    #pragma unroll
    for (int kt = 0; kt < 4; ++kt)
      iF[mm][kt] = *(const bf16x8*)&scr[mm*16 + c][kt*32 + q*8];

  // ---- GEMM2: h^T = relu(Wc . [cust|info]^T + b_comb) ----
  #pragma unroll
  for (int t = 0; t < 8; ++t){ acc[t][0] = fz; acc[t][1] = fz; }
  #pragma unroll
  for (int t = 0; t < 8; ++t){
    const int wrow = (t*16 + c) * 256 + q*8;
    #pragma unroll
    for (int kt = 0; kt < 4; ++kt){
      bf16x8 wcf = *(const bf16x8*)(wc + wrow + kt*32);
      #pragma unroll
      for (int mm = 0; mm < 2; ++mm)
        acc[t][mm] = __builtin_amdgcn_mfma_f32_16x16x32_bf16(wcf, cF[mm][kt], acc[t][mm], 0, 0, 0);
    }
    #pragma unroll
    for (int kt = 0; kt < 4; ++kt){
      bf16x8 wcf = *(const bf16x8*)(wc + wrow + 128 + kt*32);
      #pragma unroll
      for (int mm = 0; mm < 2; ++mm)
        acc[t][mm] = __builtin_amdgcn_mfma_f32_16x16x32_bf16(wcf, iF[mm][kt], acc[t][mm], 0, 0, 0);
    }
  }

  // h = relu(acc + bc) -> scratch (overwrites info; same-wave in-order DS)
  #pragma unroll
  for (int t = 0; t < 8; ++t){
    #pragma unroll
    for (int mm = 0; mm < 2; ++mm){
      ushort4 u;
      u.x = f2bf(fmaxf(acc[t][mm][0] + bcv[t][0], 0.f));
      u.y = f2bf(fmaxf(acc[t][mm][1] + bcv[t][1], 0.f));
      u.z = f2bf(fmaxf(acc[t][mm][2] + bcv[t][2], 0.f));
      u.w = f2bf(fmaxf(acc[t][mm][3] + bcv[t][3], 0.f));
      *(ushort4*)&scr[mm*16 + c][t*16 + q*4] = u;
    }
  }
  LGKM0();

  bf16x8 hF[2][4];
  #pragma unroll
  for (int mm = 0; mm < 2; ++mm)
    #pragma unroll
    for (int kt = 0; kt < 4; ++kt)
      hF[mm][kt] = *(const bf16x8*)&scr[mm*16 + c][kt*32 + q*8];

  // ---- GEMM3: h2^T = Wff . h^T ----
  #pragma unroll
  for (int t = 0; t < 8; ++t){ acc[t][0] = fz; acc[t][1] = fz; }
  #pragma unroll
  for (int t = 0; t < 8; ++t){
    const int wrow = (t*16 + c) * DD + q*8;
    #pragma unroll
    for (int kt = 0; kt < 4; ++kt){
      bf16x8 wff = *(const bf16x8*)(wf + wrow + kt*32);
      #pragma unroll
      for (int mm = 0; mm < 2; ++mm)
        acc[t][mm] = __builtin_amdgcn_mfma_f32_16x16x32_bf16(wff, hF[mm][kt], acc[t][mm], 0, 0, 0);
    }
  }

  // cust frags -> scratch [m][k] (h already consumed into regs)
  #pragma unroll
  for (int mm = 0; mm < 2; ++mm)
    #pragma unroll
    for (int kt = 0; kt < 4; ++kt)
      *(bf16x8*)&scr[mm*16 + c][kt*32 + q*8] = cF[mm][kt];
  LGKM0();

  // ---- residual + stats + added->scratch ----
  const bool ok0 = (R0 + c) < NN;
  const bool ok1 = (R0 + 16 + c) < NN;
  float s[8][4], sq[8][4];
  #pragma unroll
  for (int t = 0; t < 8; ++t)
    #pragma unroll
    for (int r = 0; r < 4; ++r){ s[t][r] = 0.f; sq[t][r] = 0.f; }

  #pragma unroll
  for (int t = 0; t < 8; ++t){
    #pragma unroll
    for (int mm = 0; mm < 2; ++mm){
      ushort4 cu = *(const ushort4*)&scr[mm*16 + c][t*16 + q*4];
      float v0 = acc[t][mm][0] + bfv[t][0] + bf2f(cu.x);
      float v1 = acc[t][mm][1] + bfv[t][1] + bf2f(cu.y);
      float v2 = acc[t][mm][2] + bfv[t][2] + bf2f(cu.z);
      float v3 = acc[t][mm][3] + bfv[t][3] + bf2f(cu.w);
      bool ok = mm ? ok1 : ok0;
      if (ok){
        s[t][0] += v0; sq[t][0] += v0*v0;
        s[t][1] += v1; sq[t][1] += v1*v1;
        s[t][2] += v2; sq[t][2] += v2*v2;
        s[t][3] += v3; sq[t][3] += v3*v3;
      }
      ushort4 au;
      au.x = f2bf(v0); au.y = f2bf(v1); au.z = f2bf(v2); au.w = f2bf(v3);
      *(ushort4*)&scr[mm*16 + c][t*16 + q*4] = au;
      if (!BF && ok){
        float4 fv = {v0, v1, v2, v3};
        *(float4*)(out + (size_t)b * EROW + (size_t)(R0 + mm*16 + c + 1) * DD + t*16 + q*4) = fv;
      }
    }
  }

  // butterfly over the 16 c-lanes (q-groups own disjoint n sets)
  #pragma unroll
  for (int t = 0; t < 8; ++t){
    #pragma unroll
    for (int r = 0; r < 4; ++r){
      float a = s[t][r], d = sq[t][r];
      a += __shfl_xor(a, 1); a += __shfl_xor(a, 2); a += __shfl_xor(a, 4); a += __shfl_xor(a, 8);
      d += __shfl_xor(d, 1); d += __shfl_xor(d, 2); d += __shfl_xor(d, 4); d += __shfl_xor(d, 8);
      s[t][r] = a; sq[t][r] = d;
    }
  }
  if (c == 0){
    #pragma unroll
    for (int t = 0; t < 8; ++t){
      #pragma unroll
      for (int r = 0; r < 4; ++r){
        int n = t*16 + q*4 + r;
        atomicAdd(&sums [b * DD + n], s[t][r]);
        atomicAdd(&sumsq[b * DD + n], sq[t][r]);
      }
    }
  }

  // ---- coalesced copy-out of added (bf16) ----
  if (BF){
    LGKM0();
    const int row = lane >> 1, half = lane & 1;
    if (R0 + row < NN){
      u16* dst = abuf + ((size_t)b * NN + R0 + row) * DD + half*64;
      #pragma unroll
      for (int j = 0; j < 8; ++j)
        *(bf16x8*)(dst + j*8) = *(const bf16x8*)&scr[row][half*64 + j*8];
    }
  }
}

// ---------------- k2 (bf path): stats inline + read bf16 added, write fp32 out ----------------
__global__ __launch_bounds__(256) void k2_bf(
    const u16* __restrict__ abuf, const float* __restrict__ sums,
    const float* __restrict__ sumsq, const float* __restrict__ nw,
    const float* __restrict__ nb, float* __restrict__ out)
{
  __shared__ float ssc[128], ssh[128];
  const int b = blockIdx.y;
  const int t = threadIdx.x;
  if (t < 128){
    float mean = sums[b * DD + t] * (1.f / NN);
    float var  = sumsq[b * DD + t] * (1.f / NN) - mean * mean;
    float inv  = rsqrtf(var + 1e-5f);
    float sc   = inv * nw[t];
    ssc[t] = sc;
    ssh[t] = nb[t] - mean * sc;
  }
  __syncthreads();
  const int e = (blockIdx.x * 256 + t) * 8;   // within-batch flat index
  if (e >= CROW) return;
  const int d = e & 127;
  const uint4 raw = *(const uint4*)(abuf + (size_t)b * CROW + e);
  const float4 s0 = *(const float4*)&ssc[d];
  const float4 s1 = *(const float4*)&ssc[d + 4];
  const float4 h0 = *(const float4*)&ssh[d];
  const float4 h1 = *(const float4*)&ssh[d + 4];
  float4 v0, v1;
  v0.x = __builtin_bit_cast(float, raw.x << 16);
  v0.y = __builtin_bit_cast(float, raw.x & 0xffff0000u);
  v0.z = __builtin_bit_cast(float, raw.y << 16);
  v0.w = __builtin_bit_cast(float, raw.y & 0xffff0000u);
  v1.x = __builtin_bit_cast(float, raw.z << 16);
  v1.y = __builtin_bit_cast(float, raw.z & 0xffff0000u);
  v1.z = __builtin_bit_cast(float, raw.w << 16);
  v1.w = __builtin_bit_cast(float, raw.w & 0xffff0000u);
  v0.x = v0.x * s0.x + h0.x; v0.y = v0.y * s0.y + h0.y;
  v0.z = v0.z * s0.z + h0.z; v0.w = v0.w * s0.w + h0.w;
  v1.x = v1.x * s1.x + h1.x; v1.y = v1.y * s1.y + h1.y;
  v1.z = v1.z * s1.z + h1.z; v1.w = v1.w * s1.w + h1.w;
  float4* p = (float4*)(out + (size_t)b * EROW + DD + e);
  p[0] = v0; p[1] = v1;
}

// ---------------- k2 (fallback): stats inline + in-place RMW layernorm ----------------
__global__ __launch_bounds__(256) void k2_rmw(
    float* __restrict__ out, const float* __restrict__ sums,
    const float* __restrict__ sumsq, const float* __restrict__ nw,
    const float* __restrict__ nb)
{
  __shared__ float ssc[128], ssh[128];
  const int b = blockIdx.y;
  const int t = threadIdx.x;
  if (t < 128){
    float mean = sums[b * DD + t] * (1.f / NN);
    float var  = sumsq[b * DD + t] * (1.f / NN) - mean * mean;
    float inv  = rsqrtf(var + 1e-5f);
    float sc   = inv * nw[t];
    ssc[t] = sc;
    ssh[t] = nb[t] - mean * sc;
  }
  __syncthreads();
  const int e = (blockIdx.x * 256 + t) * 8;
  if (e >= CROW) return;
  const int d = e & 127;
  const float4 s0 = *(const float4*)&ssc[d];
  const float4 s1 = *(const float4*)&ssc[d + 4];
  const float4 h0 = *(const float4*)&ssh[d];
  const float4 h1 = *(const float4*)&ssh[d + 4];
  float4* p = (float4*)(out + (size_t)b * EROW + DD + e);
  float4 v0 = p[0], v1 = p[1];
  v0.x = v0.x * s0.x + h0.x; v0.y = v0.y * s0.y + h0.y;
  v0.z = v0.z * s0.z + h0.z; v0.w = v0.w * s0.w + h0.w;
  v1.x = v1.x * s1.x + h1.x; v1.y = v1.y * s1.y + h1.y;
  v1.z = v1.z * s1.z + h1.z; v1.w = v1.w * s1.w + h1.w;
  p[0] = v0; p[1] = v1;
}

extern "C" void kernel_launch(void* const* d_in, const int* in_sizes, int n_in,
                              void* d_out, int out_size, void* d_ws, size_t ws_size,
                              hipStream_t stream)
{
  const int2*  sol  = (const int2*) d_in[2];
  const float* emb  = (const float*)d_in[3];
  const float* wl   = (const float*)d_in[4];
  const float* wr   = (const float*)d_in[5];
  const float* wcmb = (const float*)d_in[6];
  const float* bcmb = (const float*)d_in[7];
  const float* wff  = (const float*)d_in[8];
  const float* bff  = (const float*)d_in[9];
  const float* nw   = (const float*)d_in[10];
  const float* nb   = (const float*)d_in[11];
  float* out = (float*)d_out;

  u16*   wbf   = (u16*)d_ws;                           // 81920 bf16 = 163840 B
  float* sums  = (float*)((char*)d_ws + 163840);       // 8192 f32
  float* sumsq = (float*)((char*)d_ws + 196608);       // 8192 f32
  u16*   abuf  = (u16*)((char*)d_ws + 294912);         // 64*5000*128 bf16 = 81.92 MB

  const size_t need = 294912ull + (size_t)BB * NN * DD * 2;
  const bool bfpath = (ws_size >= need);

  k0_prep <<<320, 256, 0, stream>>>(wl, wr, wcmb, wff, emb, out, wbf, sums, sumsq);
  if (bfpath){
    k1_main<true> <<<dim3(40, BB), 256, 0, stream>>>(sol, emb, wbf, bcmb, bff, out, abuf, sums, sumsq);
    k2_bf  <<<dim3(313, 64), 256, 0, stream>>>(abuf, sums, sumsq, nw, nb, out);
  } else {
    k1_main<false><<<dim3(40, BB), 256, 0, stream>>>(sol, emb, wbf, bcmb, bff, out, abuf, sums, sumsq);
    k2_rmw <<<dim3(313, 64), 256, 0, stream>>>(out, sums, sumsq, nw, nb);
  }
}